// Round 5
// baseline (220.473 us; speedup 1.0000x reference)
//
#include <hip/hip_runtime.h>
#include <hip/hip_bf16.h>

// (T, H, O) = (32768, 1024, 1024)
constexpr int T = 32768;
constexpr int H = 1024;

constexpr int NB1 = 1024;          // blocks in fused pass 1 (4/CU exactly)
constexpr int RPB = T / NB1;       // rows per block = 32
constexpr int CH  = 8;             // rows per chunk; 4 chunks
constexpr int NCH = RPB / CH;

// ws layout (floats)
constexpr int MB_OFF  = 256;               // per-block running max  (NB1)
constexpr int LB_OFF  = MB_OFF + NB1;      // per-block running sum  (NB1)
constexpr int SC_OFF  = 4096;              // raw scores (T)
constexpr int ACC_OFF = SC_OFF + T;        // per-block partial outputs (NB1*H)

// ---------------- Pass 1: fused scores + online-softmax partial output ------
// 256 threads/block; thread t owns columns 4t..4t+3; block owns 32 rows.
// enc element read from HBM exactly once. Chunk c+1's loads are issued BEFORE
// chunk c's reduction (prefetch), so HBM stays busy through the math phase.
// One barrier per chunk via double-buffered LDS:
//   chunk c writes red[c&1], barrier, reads red[c&1]; chunk c+1 writes the
//   other buffer. A wave can only rewrite red[c&1] (at chunk c+2) after
//   passing chunk c+1's barrier, which every wave reaches only after its
//   chunk-c reads are done -> single barrier is race-free.
__global__ __launch_bounds__(256, 4) void fused_pass1(
    const float* __restrict__ enc, const float* __restrict__ w_enc,
    float* __restrict__ scores, float* __restrict__ mb, float* __restrict__ lb,
    float* __restrict__ accs, float* __restrict__ out) {
    const int b    = blockIdx.x;
    const int tid  = threadIdx.x;
    const int wave = tid >> 6;
    const int lane = tid & 63;
    const int row0 = b * RPB;

    if (b < 4) out[b * 256 + tid] = 0.f;   // d_out[0..H) zero (poisoned 0xAA)

    const float4 w4 = *reinterpret_cast<const float4*>(w_enc + 4 * tid);

    __shared__ float red[2][4][CH];

    float  m = -3.0e38f, l = 0.f;
    float4 acc = make_float4(0.f, 0.f, 0.f, 0.f);

    float4 e[CH], en[CH];
#pragma unroll
    for (int r = 0; r < CH; ++r)
        e[r] = *reinterpret_cast<const float4*>(enc + (size_t)(row0 + r) * H + 4 * tid);

    for (int c = 0; c < NCH; ++c) {
        // ---- prefetch next chunk (keeps vmcnt>0 through the math below) ----
        if (c + 1 < NCH) {
            const int rn = row0 + (c + 1) * CH;
#pragma unroll
            for (int r = 0; r < CH; ++r)
                en[r] = *reinterpret_cast<const float4*>(enc + (size_t)(rn + r) * H + 4 * tid);
        }

        // ---- per-row dot partials + wave butterfly ----
        float p[CH];
#pragma unroll
        for (int r = 0; r < CH; ++r)
            p[r] = e[r].x * w4.x + e[r].y * w4.y + e[r].z * w4.z + e[r].w * w4.w;
#pragma unroll
        for (int r = 0; r < CH; ++r) {
#pragma unroll
            for (int off = 32; off; off >>= 1) p[r] += __shfl_xor(p[r], off);
        }
        if (lane == 0) {
#pragma unroll
            for (int r = 0; r < CH; ++r) red[c & 1][wave][r] = p[r];
        }
        __syncthreads();

        float s[CH];
        float mc = -3.0e38f;
#pragma unroll
        for (int r = 0; r < CH; ++r) {
            s[r] = red[c & 1][0][r] + red[c & 1][1][r] + red[c & 1][2][r] + red[c & 1][3][r];
            mc = fmaxf(mc, s[r]);
        }

        // ---- online-softmax update ----
        const float mn = fmaxf(m, mc);
        const float rs = __expf(m - mn);      // first chunk: exp(-inf) -> 0
        l *= rs;
        acc.x *= rs; acc.y *= rs; acc.z *= rs; acc.w *= rs;
#pragma unroll
        for (int r = 0; r < CH; ++r) {
            const float wgt = __expf(s[r] - mn);
            l += wgt;
            acc.x = fmaf(wgt, e[r].x, acc.x);
            acc.y = fmaf(wgt, e[r].y, acc.y);
            acc.z = fmaf(wgt, e[r].z, acc.z);
            acc.w = fmaf(wgt, e[r].w, acc.w);
        }
        m = mn;

        if (tid == 0) {
#pragma unroll
            for (int r = 0; r < CH; ++r) scores[row0 + c * CH + r] = s[r];
        }

        if (c + 1 < NCH) {
#pragma unroll
            for (int r = 0; r < CH; ++r) e[r] = en[r];
        }
    }

    *reinterpret_cast<float4*>(accs + (size_t)b * H + 4 * tid) = acc;
    if (tid == 0) { mb[b] = m; lb[b] = l; }
}

// ---------------- Pass 2: redundant global (M,L) + combine + weights --------
// Every block recomputes M, L from mb/lb (8 KB, L2-hot) — cheaper than a
// dedicated single-block kernel + extra launch gap.
// blocks 0..63 : out[h] += 16 rescaled partial vectors (atomic)
// blocks 64..95: normalized weights, 1024 t-values each
__global__ __launch_bounds__(256) void combine2(
    const float* __restrict__ mb, const float* __restrict__ lb,
    const float* __restrict__ accs, const float* __restrict__ scores,
    float* __restrict__ out, float* __restrict__ wout) {
    __shared__ float sm[8];
    const int tid  = threadIdx.x;
    const int wave = tid >> 6;
    const int lane = tid & 63;

    float m = fmaxf(fmaxf(mb[tid], mb[tid + 256]),
                    fmaxf(mb[tid + 512], mb[tid + 768]));
#pragma unroll
    for (int off = 32; off; off >>= 1) m = fmaxf(m, __shfl_xor(m, off));
    if (lane == 0) sm[wave] = m;
    __syncthreads();
    const float M = fmaxf(fmaxf(sm[0], sm[1]), fmaxf(sm[2], sm[3]));

    float l = lb[tid]       * __expf(mb[tid]       - M)
            + lb[tid + 256] * __expf(mb[tid + 256] - M)
            + lb[tid + 512] * __expf(mb[tid + 512] - M)
            + lb[tid + 768] * __expf(mb[tid + 768] - M);
#pragma unroll
    for (int off = 32; off; off >>= 1) l += __shfl_xor(l, off);
    if (lane == 0) sm[4 + wave] = l;
    __syncthreads();
    const float rL = 1.f / (sm[4] + sm[5] + sm[6] + sm[7]);

    if (blockIdx.x < 64) {
        const int b0 = blockIdx.x * 16;
        float4 a = make_float4(0.f, 0.f, 0.f, 0.f);
#pragma unroll 4
        for (int i = 0; i < 16; ++i) {
            const float wsc = __expf(mb[b0 + i] - M) * rL;
            float4 v = *reinterpret_cast<const float4*>(accs + (size_t)(b0 + i) * H + 4 * tid);
            a.x = fmaf(wsc, v.x, a.x);
            a.y = fmaf(wsc, v.y, a.y);
            a.z = fmaf(wsc, v.z, a.z);
            a.w = fmaf(wsc, v.w, a.w);
        }
        atomicAdd(&out[4 * tid + 0], a.x);
        atomicAdd(&out[4 * tid + 1], a.y);
        atomicAdd(&out[4 * tid + 2], a.z);
        atomicAdd(&out[4 * tid + 3], a.w);
    } else {
        const int t0 = (blockIdx.x - 64) * 1024 + 4 * tid;
        float4 sv = *reinterpret_cast<const float4*>(scores + t0);
        float4 wv;
        wv.x = __expf(sv.x - M) * rL;
        wv.y = __expf(sv.y - M) * rL;
        wv.z = __expf(sv.z - M) * rL;
        wv.w = __expf(sv.w - M) * rL;
        *reinterpret_cast<float4*>(wout + t0) = wv;
    }
}

extern "C" void kernel_launch(void* const* d_in, const int* in_sizes, int n_in,
                              void* d_out, int out_size, void* d_ws, size_t ws_size,
                              hipStream_t stream) {
    // inputs: dec_h (1024), enc (T*H), attn_w (2048), attn_b (1)
    // dec_h/attn_b shift all scores by one constant -> cancels in softmax.
    const float* enc    = (const float*)d_in[1];
    const float* attn_w = (const float*)d_in[2];
    const float* w_enc  = attn_w + 1024;

    float* out  = (float*)d_out;       // [0..H): output vector
    float* wout = (float*)d_out + H;   // [H..H+T): normalized weights

    float* ws     = (float*)d_ws;
    float* mb     = ws + MB_OFF;
    float* lb     = ws + LB_OFF;
    float* scores = ws + SC_OFF;
    float* accs   = ws + ACC_OFF;

    fused_pass1<<<NB1, 256, 0, stream>>>(enc, w_enc, scores, mb, lb, accs, out);
    combine2<<<96, 256, 0, stream>>>(mb, lb, accs, scores, out, wout);
}

// Round 6
// 210.958 us; speedup vs baseline: 1.0451x; 1.0451x over previous
//
#include <hip/hip_runtime.h>
#include <hip/hip_bf16.h>

// (T, H, O) = (32768, 1024, 1024)
constexpr int T = 32768;
constexpr int H = 1024;

constexpr int NB1 = 1024;          // blocks in fused pass 1
constexpr int RPB = T / NB1;       // rows per block = 32
constexpr int CH  = 8;             // rows per chunk; 4 chunks
constexpr int NCH = RPB / CH;

// ws layout (floats)
constexpr int MB_OFF  = 256;               // per-block running max  (NB1)
constexpr int LB_OFF  = MB_OFF + NB1;      // per-block running sum  (NB1)
constexpr int SC_OFF  = 4096;              // raw scores (T)
constexpr int ACC_OFF = SC_OFF + T;        // per-block partial outputs (NB1*H)

// ---------------- Pass 1: fused scores + online-softmax partial output ------
// 256 threads/block; thread t owns columns 4t..4t+3; block owns 32 rows.
// Each enc element is read from HBM exactly once (registers serve both the
// score dot and the weighted accumulation). ONE barrier per chunk via
// double-buffered LDS: chunk c writes red[c&1], barrier, reads red[c&1].
// All chunk-c reads precede chunk c+1's barrier; the next write to red[c&1]
// (chunk c+2) happens only after that barrier -> race-free.
__global__ __launch_bounds__(256) void fused_pass1(
    const float* __restrict__ enc, const float* __restrict__ w_enc,
    float* __restrict__ scores, float* __restrict__ mb, float* __restrict__ lb,
    float* __restrict__ accs, float* __restrict__ out) {
    const int b    = blockIdx.x;
    const int tid  = threadIdx.x;
    const int wave = tid >> 6;
    const int lane = tid & 63;
    const int row0 = b * RPB;

    if (b < 4) out[b * 256 + tid] = 0.f;   // d_out[0..H) zero (poisoned 0xAA)

    const float4 w4 = *reinterpret_cast<const float4*>(w_enc + 4 * tid);

    __shared__ float red[2][4][CH];

    float  m = -3.0e38f, l = 0.f;
    float4 acc = make_float4(0.f, 0.f, 0.f, 0.f);

    for (int c = 0; c < NCH; ++c) {
        const int r0 = row0 + c * CH;
        float4 e[CH];
        float  p[CH];
#pragma unroll
        for (int r = 0; r < CH; ++r) {
            e[r] = *reinterpret_cast<const float4*>(enc + (size_t)(r0 + r) * H + 4 * tid);
            p[r] = e[r].x * w4.x + e[r].y * w4.y + e[r].z * w4.z + e[r].w * w4.w;
        }
        // wave butterfly: every lane ends with the wave-sum of each row
#pragma unroll
        for (int r = 0; r < CH; ++r) {
#pragma unroll
            for (int off = 32; off; off >>= 1) p[r] += __shfl_xor(p[r], off);
        }
        if (lane == 0) {
#pragma unroll
            for (int r = 0; r < CH; ++r) red[c & 1][wave][r] = p[r];
        }
        __syncthreads();

        float s[CH];
        float mc = -3.0e38f;
#pragma unroll
        for (int r = 0; r < CH; ++r) {
            s[r] = red[c & 1][0][r] + red[c & 1][1][r] + red[c & 1][2][r] + red[c & 1][3][r];
            mc = fmaxf(mc, s[r]);
        }

        const float mn = fmaxf(m, mc);
        const float rs = __expf(m - mn);      // first chunk: exp(-inf) -> 0
        l *= rs;
        acc.x *= rs; acc.y *= rs; acc.z *= rs; acc.w *= rs;
#pragma unroll
        for (int r = 0; r < CH; ++r) {
            const float wgt = __expf(s[r] - mn);
            l += wgt;
            acc.x = fmaf(wgt, e[r].x, acc.x);
            acc.y = fmaf(wgt, e[r].y, acc.y);
            acc.z = fmaf(wgt, e[r].z, acc.z);
            acc.w = fmaf(wgt, e[r].w, acc.w);
        }
        m = mn;

        if (tid == 0) {
#pragma unroll
            for (int r = 0; r < CH; ++r) scores[r0 + r] = s[r];
        }
    }

    *reinterpret_cast<float4*>(accs + (size_t)b * H + 4 * tid) = acc;
    if (tid == 0) { mb[b] = m; lb[b] = l; }
}

// ---------------- Pass 2: redundant global (M,L) + combine + weights --------
// Every block recomputes M, L from mb/lb (8 KB, L2-hot) — cheaper than a
// dedicated single-block kernel + extra launch gap.
// blocks 0..63 : out[h] += 16 rescaled partial vectors (atomic)
// blocks 64..95: normalized weights, 1024 t-values each
__global__ __launch_bounds__(256) void combine2(
    const float* __restrict__ mb, const float* __restrict__ lb,
    const float* __restrict__ accs, const float* __restrict__ scores,
    float* __restrict__ out, float* __restrict__ wout) {
    __shared__ float sm[8];
    const int tid  = threadIdx.x;
    const int wave = tid >> 6;
    const int lane = tid & 63;

    float m = fmaxf(fmaxf(mb[tid], mb[tid + 256]),
                    fmaxf(mb[tid + 512], mb[tid + 768]));
#pragma unroll
    for (int off = 32; off; off >>= 1) m = fmaxf(m, __shfl_xor(m, off));
    if (lane == 0) sm[wave] = m;
    __syncthreads();
    const float M = fmaxf(fmaxf(sm[0], sm[1]), fmaxf(sm[2], sm[3]));

    float l = lb[tid]       * __expf(mb[tid]       - M)
            + lb[tid + 256] * __expf(mb[tid + 256] - M)
            + lb[tid + 512] * __expf(mb[tid + 512] - M)
            + lb[tid + 768] * __expf(mb[tid + 768] - M);
#pragma unroll
    for (int off = 32; off; off >>= 1) l += __shfl_xor(l, off);
    if (lane == 0) sm[4 + wave] = l;
    __syncthreads();
    const float rL = 1.f / (sm[4] + sm[5] + sm[6] + sm[7]);

    if (blockIdx.x < 64) {
        const int b0 = blockIdx.x * 16;
        float4 a = make_float4(0.f, 0.f, 0.f, 0.f);
#pragma unroll 4
        for (int i = 0; i < 16; ++i) {
            const float wsc = __expf(mb[b0 + i] - M) * rL;
            float4 v = *reinterpret_cast<const float4*>(accs + (size_t)(b0 + i) * H + 4 * tid);
            a.x = fmaf(wsc, v.x, a.x);
            a.y = fmaf(wsc, v.y, a.y);
            a.z = fmaf(wsc, v.z, a.z);
            a.w = fmaf(wsc, v.w, a.w);
        }
        atomicAdd(&out[4 * tid + 0], a.x);
        atomicAdd(&out[4 * tid + 1], a.y);
        atomicAdd(&out[4 * tid + 2], a.z);
        atomicAdd(&out[4 * tid + 3], a.w);
    } else {
        const int t0 = (blockIdx.x - 64) * 1024 + 4 * tid;
        float4 sv = *reinterpret_cast<const float4*>(scores + t0);
        float4 wv;
        wv.x = __expf(sv.x - M) * rL;
        wv.y = __expf(sv.y - M) * rL;
        wv.z = __expf(sv.z - M) * rL;
        wv.w = __expf(sv.w - M) * rL;
        *reinterpret_cast<float4*>(wout + t0) = wv;
    }
}

extern "C" void kernel_launch(void* const* d_in, const int* in_sizes, int n_in,
                              void* d_out, int out_size, void* d_ws, size_t ws_size,
                              hipStream_t stream) {
    // inputs: dec_h (1024), enc (T*H), attn_w (2048), attn_b (1)
    // dec_h/attn_b shift all scores by one constant -> cancels in softmax.
    const float* enc    = (const float*)d_in[1];
    const float* attn_w = (const float*)d_in[2];
    const float* w_enc  = attn_w + 1024;

    float* out  = (float*)d_out;       // [0..H): output vector
    float* wout = (float*)d_out + H;   // [H..H+T): normalized weights

    float* ws     = (float*)d_ws;
    float* mb     = ws + MB_OFF;
    float* lb     = ws + LB_OFF;
    float* scores = ws + SC_OFF;
    float* accs   = ws + ACC_OFF;

    fused_pass1<<<NB1, 256, 0, stream>>>(enc, w_enc, scores, mb, lb, accs, out);
    combine2<<<96, 256, 0, stream>>>(mb, lb, accs, scores, out, wout);
}